// Round 1
// baseline (119.171 us; speedup 1.0000x reference)
//
#include <hip/hip_runtime.h>
#include <math.h>

#define N_SAMPLES 8192
#define DIM 128
#define NCLS 1024
#define MARGIN_V 0.3f

// ---- monotonic float<->uint encoding for atomic max/min on floats ----
__device__ __forceinline__ unsigned enc_f(float f) {
  unsigned b = __float_as_uint(f);
  return (b & 0x80000000u) ? ~b : (b | 0x80000000u);
}
__device__ __forceinline__ float dec_f(unsigned u) {
  unsigned b = (u & 0x80000000u) ? (u & 0x7FFFFFFFu) : ~u;
  return __uint_as_float(b);
}

// K1: init counts/cursor to 0, dp/dn sentinels
__global__ void init_kernel(int* counts, int* cursor, unsigned* dpbits, unsigned* dnbits) {
  int i = blockIdx.x * 256 + threadIdx.x;
  if (i < NCLS) {
    counts[i] = 0;
    cursor[i] = 0;
    dpbits[i] = enc_f(-INFINITY);  // max identity
    dnbits[i] = enc_f(INFINITY);   // min identity
  }
}

// K2: x2[j] = ||x_j||^2, counts[t_j]++  (one wave per row)
__global__ void x2_counts_kernel(const float* __restrict__ inputs, const int* __restrict__ targets,
                                 float* __restrict__ x2, int* counts) {
  int wave = threadIdx.x >> 6;
  int lane = threadIdx.x & 63;
  int row = blockIdx.x * 4 + wave;
  const float2* p = (const float2*)(inputs + (size_t)row * DIM);
  float2 v = p[lane];
  float s = v.x * v.x + v.y * v.y;
  #pragma unroll
  for (int sh = 32; sh > 0; sh >>= 1) s += __shfl_down(s, sh);
  if (lane == 0) {
    x2[row] = s;
    atomicAdd(&counts[targets[row]], 1);
  }
}

// K3: exclusive prefix-sum of counts -> offsets (single block, 1024 threads)
__global__ void scan_kernel(const int* __restrict__ counts, int* __restrict__ offsets) {
  __shared__ int buf[NCLS];
  int t = threadIdx.x;
  int v = counts[t];
  buf[t] = v;
  __syncthreads();
  for (int off = 1; off < NCLS; off <<= 1) {
    int add = (t >= off) ? buf[t - off] : 0;
    __syncthreads();
    buf[t] += add;
    __syncthreads();
  }
  offsets[t] = buf[t] - v;  // exclusive
}

// K4: scatter sample indices into per-class member lists
__global__ void scatter_kernel(const int* __restrict__ targets, const int* __restrict__ offsets,
                               int* cursor, int* __restrict__ members) {
  int i = blockIdx.x * 256 + threadIdx.x;
  if (i < N_SAMPLES) {
    int t = targets[i];
    int pos = atomicAdd(&cursor[t], 1);
    members[offsets[t] + pos] = i;
  }
}

// K5: per-class center + ||center||^2  (one block of 128 threads per class)
__global__ void centers_kernel(const float* __restrict__ inputs, const int* __restrict__ members,
                               const int* __restrict__ offsets, const int* __restrict__ counts,
                               float* __restrict__ centers, float* __restrict__ c2) {
  int c = blockIdx.x;
  int d = threadIdx.x;  // 0..127
  int off = offsets[c];
  int cnt = counts[c];
  float acc = 0.f;
  for (int m = 0; m < cnt; m++) {
    int idx = members[off + m];
    acc += inputs[(size_t)idx * DIM + d];
  }
  float ctr = (cnt > 0) ? acc / (float)cnt : 0.f;
  centers[(size_t)c * DIM + d] = ctr;
  float v = ctr * ctr;
  #pragma unroll
  for (int sh = 32; sh > 0; sh >>= 1) v += __shfl_down(v, sh);
  __shared__ float ws[2];
  if ((d & 63) == 0) ws[d >> 6] = v;
  __syncthreads();
  if (d == 0) c2[c] = ws[0] + ws[1];
}

// K6: fused "GEMM + masked row max/min".
// Tile: 128 classes x 128 samples per block, K chunked by 32 through LDS.
// Thread tile 8x8; c-rows strided by 16 (broadcast reads), j-rows strided by 16
// (2-way bank alias = free).
__global__ __launch_bounds__(256) void dist_kernel(
    const float* __restrict__ inputs, const float* __restrict__ centers,
    const float* __restrict__ x2, const float* __restrict__ c2,
    const int* __restrict__ targets, unsigned* dpbits, unsigned* dnbits) {
  __shared__ float sC[128][36];  // 36-float stride: float4-aligned, banks 4*row
  __shared__ float sX[128][36];
  __shared__ int stgt[128];

  int tid = threadIdx.x;
  int jbase = blockIdx.x * 128;
  int cbase = blockIdx.y * 128;
  int tx = tid & 15;   // j group
  int ty = tid >> 4;   // c group (0..15)

  if (tid < 128) stgt[tid] = targets[jbase + tid];

  float acc[8][8];
  #pragma unroll
  for (int i = 0; i < 8; i++)
    #pragma unroll
    for (int j = 0; j < 8; j++) acc[i][j] = 0.f;

  int rf4 = tid & 7;   // float4 index within 32-float chunk row
  int rrow = tid >> 3; // 0..31

  for (int kc = 0; kc < 4; kc++) {
    __syncthreads();  // protect LDS from previous chunk's readers
    #pragma unroll
    for (int p = 0; p < 4; p++) {
      int row = rrow + p * 32;
      const float4 cv = *(const float4*)(centers + (size_t)(cbase + row) * DIM + kc * 32 + rf4 * 4);
      *(float4*)(&sC[row][rf4 * 4]) = cv;
      const float4 xv = *(const float4*)(inputs + (size_t)(jbase + row) * DIM + kc * 32 + rf4 * 4);
      *(float4*)(&sX[row][rf4 * 4]) = xv;
    }
    __syncthreads();

    for (int k4 = 0; k4 < 8; k4++) {
      float4 b[8];
      #pragma unroll
      for (int j = 0; j < 8; j++) b[j] = *(const float4*)(&sX[tx + 16 * j][k4 * 4]);
      #pragma unroll
      for (int i = 0; i < 8; i++) {
        float4 a = *(const float4*)(&sC[ty + 16 * i][k4 * 4]);
        #pragma unroll
        for (int j = 0; j < 8; j++) {
          acc[i][j] += a.x * b[j].x + a.y * b[j].y + a.z * b[j].z + a.w * b[j].w;
        }
      }
    }
  }

  // epilogue: dist2 = c2[c] + x2[j] - 2*dot; masked max (positives) / min (negatives)
  float c2r[8], x2r[8];
  int tg[8];
  #pragma unroll
  for (int i = 0; i < 8; i++) c2r[i] = c2[cbase + ty + 16 * i];
  #pragma unroll
  for (int j = 0; j < 8; j++) {
    x2r[j] = x2[jbase + tx + 16 * j];
    tg[j] = stgt[tx + 16 * j];
  }
  float pmax[8], nmin[8];
  #pragma unroll
  for (int i = 0; i < 8; i++) { pmax[i] = -INFINITY; nmin[i] = INFINITY; }
  #pragma unroll
  for (int i = 0; i < 8; i++) {
    int cg = cbase + ty + 16 * i;
    #pragma unroll
    for (int j = 0; j < 8; j++) {
      float d2 = c2r[i] + x2r[j] - 2.f * acc[i][j];
      if (tg[j] == cg) pmax[i] = fmaxf(pmax[i], d2);
      else             nmin[i] = fminf(nmin[i], d2);
    }
  }
  // reduce across the 16 tx lanes (lane bits 0..3 within the wave)
  #pragma unroll
  for (int m = 1; m < 16; m <<= 1) {
    #pragma unroll
    for (int i = 0; i < 8; i++) {
      pmax[i] = fmaxf(pmax[i], __shfl_xor(pmax[i], m));
      nmin[i] = fminf(nmin[i], __shfl_xor(nmin[i], m));
    }
  }
  if (tx == 0) {
    #pragma unroll
    for (int i = 0; i < 8; i++) {
      int cg = cbase + ty + 16 * i;
      atomicMax(&dpbits[cg], enc_f(pmax[i]));
      atomicMin(&dnbits[cg], enc_f(nmin[i]));
    }
  }
}

// K7: weighted reduce over classes -> loss, prec
__global__ void finalize_kernel(const unsigned* __restrict__ dpbits, const unsigned* __restrict__ dnbits,
                                const int* __restrict__ counts, float* __restrict__ out) {
  int t = threadIdx.x;  // 256
  float ls = 0.f, ps = 0.f;
  for (int c = t; c < NCLS; c += 256) {
    int cnt = counts[c];
    if (cnt > 0) {
      float dp = dec_f(dpbits[c]);
      float dn = dec_f(dnbits[c]);
      ls += (float)cnt * fmaxf(dp - dn + MARGIN_V, 0.f);
      ps += (float)cnt * ((dn > dp) ? 1.f : 0.f);
    }
  }
  #pragma unroll
  for (int sh = 32; sh > 0; sh >>= 1) {
    ls += __shfl_down(ls, sh);
    ps += __shfl_down(ps, sh);
  }
  __shared__ float sl[4], sp[4];
  int wave = t >> 6, lane = t & 63;
  if (lane == 0) { sl[wave] = ls; sp[wave] = ps; }
  __syncthreads();
  if (t == 0) {
    out[0] = (sl[0] + sl[1] + sl[2] + sl[3]) / (float)N_SAMPLES;
    out[1] = (sp[0] + sp[1] + sp[2] + sp[3]) / (float)N_SAMPLES;
  }
}

extern "C" void kernel_launch(void* const* d_in, const int* in_sizes, int n_in,
                              void* d_out, int out_size, void* d_ws, size_t ws_size,
                              hipStream_t stream) {
  const float* inputs = (const float*)d_in[0];
  const int* targets = (const int*)d_in[1];
  float* out = (float*)d_out;

  // workspace carve-up (all re-poisoned 0xAA before every launch -> init everything we read)
  char* w = (char*)d_ws;
  float* x2 = (float*)w;        w += (size_t)N_SAMPLES * 4;
  float* centers = (float*)w;   w += (size_t)NCLS * DIM * 4;
  float* c2 = (float*)w;        w += (size_t)NCLS * 4;
  int* counts = (int*)w;        w += (size_t)NCLS * 4;
  int* offsets = (int*)w;       w += (size_t)NCLS * 4;
  int* cursor = (int*)w;        w += (size_t)NCLS * 4;
  int* members = (int*)w;       w += (size_t)N_SAMPLES * 4;
  unsigned* dpbits = (unsigned*)w; w += (size_t)NCLS * 4;
  unsigned* dnbits = (unsigned*)w; w += (size_t)NCLS * 4;

  init_kernel<<<4, 256, 0, stream>>>(counts, cursor, dpbits, dnbits);
  x2_counts_kernel<<<N_SAMPLES / 4, 256, 0, stream>>>(inputs, targets, x2, counts);
  scan_kernel<<<1, 1024, 0, stream>>>(counts, offsets);
  scatter_kernel<<<N_SAMPLES / 256, 256, 0, stream>>>(targets, offsets, cursor, members);
  centers_kernel<<<NCLS, 128, 0, stream>>>(inputs, members, offsets, counts, centers, c2);
  dist_kernel<<<dim3(N_SAMPLES / 128, NCLS / 128), 256, 0, stream>>>(
      inputs, centers, x2, c2, targets, dpbits, dnbits);
  finalize_kernel<<<1, 256, 0, stream>>>(dpbits, dnbits, counts, out);
}